// Round 4
// baseline (707.369 us; speedup 1.0000x reference)
//
#include <hip/hip_runtime.h>
#include <stdint.h>

#define NB 32
#define NS 2048
#define NE 1024   // ENC
#define ND 1024   // DEC
#define NA 1024   // ATT
#define MROWS (NB * NS)   // 65536

typedef float f32x4 __attribute__((ext_vector_type(4)));
typedef __bf16 bf16x8 __attribute__((ext_vector_type(8)));
typedef int i32x4 __attribute__((ext_vector_type(4)));
typedef unsigned short u16x4 __attribute__((ext_vector_type(4)));

typedef __attribute__((address_space(3))) unsigned int lds_u32;
typedef __attribute__((address_space(1))) unsigned int glb_u32;

__device__ __forceinline__ unsigned short f32_bf16(float x){
  unsigned int u = __float_as_uint(x);
  unsigned int r = (u + 0x7fffu + ((u >> 16) & 1u)) >> 16;
  return (unsigned short)r;
}
__device__ __forceinline__ float bf16_f32(unsigned short h){
  return __uint_as_float(((unsigned int)h) << 16);
}
__device__ __forceinline__ float tanh_fast(float x){
  float ax = fabsf(x);
  float e = __expf(-2.0f * ax);
  float t = (1.0f - e) * __builtin_amdgcn_rcpf(1.0f + e);
  return x < 0.0f ? -t : t;
}
__device__ __forceinline__ void gload_lds16(const void* g, void* l){
  __builtin_amdgcn_global_load_lds((const glb_u32*)g, (lds_u32*)l, 16, 0, 0);
}
template<int N> __device__ __forceinline__ void wait_vmcnt(){
  if constexpr (N == 0)      asm volatile("s_waitcnt vmcnt(0)" ::: "memory");
  else if constexpr (N == 4) asm volatile("s_waitcnt vmcnt(4)" ::: "memory");
  else                       asm volatile("s_waitcnt vmcnt(8)" ::: "memory");
}

// ---- kernel 0: split f32 rows -> swizzled bf16 hi/lo "LDS images" ---------
// Layout: per 256-row mtile m, 64 images of 16KB (g<32: hi of k[32g,32g+32),
// g>=32: lo). Within image: byte = (rp<<7)|(c<<6)|(((kb&3)^(rp&3))<<4)|(k&7)*2
// where row r = 2*rp+c, kb = k>>3. This equals the GEMM's LDS tile layout,
// so global_load_lds staging is fully linear (rule #21 both-sides swizzle).
__global__ __launch_bounds__(256) void split_swz_kernel(
    const float* __restrict__ src, unsigned short* __restrict__ dst)
{
  const int b = blockIdx.x, t = threadIdx.x;
  const int m = b >> 7, rp = b & 127;
  const int c = t >> 7, kb = t & 127;
  const float* sp = src + (((size_t)((m << 8) + (rp << 1) + c)) << 10) + (kb << 3);
  f32x4 v0 = *reinterpret_cast<const f32x4*>(sp);
  f32x4 v1 = *reinterpret_cast<const f32x4*>(sp + 4);
  float f[8] = {v0[0], v0[1], v0[2], v0[3], v1[0], v1[1], v1[2], v1[3]};
  unsigned short h[8], lo[8];
  #pragma unroll
  for (int j = 0; j < 8; ++j){
    h[j] = f32_bf16(f[j]);
    lo[j] = f32_bf16(f[j] - bf16_f32(h[j]));
  }
  i32x4 hp, lp;
  #pragma unroll
  for (int j = 0; j < 4; ++j){
    hp[j] = (int)((unsigned int)h[2*j]  | ((unsigned int)h[2*j+1]  << 16));
    lp[j] = (int)((unsigned int)lo[2*j] | ((unsigned int)lo[2*j+1] << 16));
  }
  const int g = kb >> 2;
  const size_t base = ((size_t)m << 19) + ((size_t)rp << 6) + (c << 5) +
                      ((size_t)((kb & 3) ^ (rp & 3)) << 3);
  *reinterpret_cast<i32x4*>(dst + base + ((size_t)g << 13))        = hp;
  *reinterpret_cast<i32x4*>(dst + base + ((size_t)(g + 32) << 13)) = lp;
}

// ---- kernel 1: V[b][a] = sum_d q[b][d]*W_d2a[a][d] -------------------------
__global__ __launch_bounds__(256) void v_kernel(
    const float* __restrict__ q, const float* __restrict__ Wd,
    float* __restrict__ V)
{
  int gw = blockIdx.x * 4 + (threadIdx.x >> 6);
  int l = threadIdx.x & 63;
  int b = gw >> 10, a = gw & 1023;
  const float* qp = q + b * ND;
  const float* wp = Wd + (size_t)a * ND;
  float s = 0.0f;
  #pragma unroll
  for (int c = 0; c < 4; ++c){
    int off = c * 256 + l * 4;
    f32x4 q4 = *reinterpret_cast<const f32x4*>(qp + off);
    f32x4 w4 = *reinterpret_cast<const f32x4*>(wp + off);
    s += q4[0]*w4[0] + q4[1]*w4[1] + q4[2]*w4[2] + q4[3]*w4[3];
  }
  #pragma unroll
  for (int off = 1; off < 64; off <<= 1) s += __shfl_xor(s, off, 64);
  if (l == 0) V[gw] = s;
}

// ---- kernel 2: 256x256 deep-pipelined bf16 GEMM, virtual K = 3072 ----------
// 96 K-tiles of 32 virtual-k. Tile t: g=t/3, ph=t%3: A-img = (ph==1? 32+g : g),
// B-img = (ph==2? 32+g : g)  [=> Ah*Bh + Al*Bh + Ah*Bl, hi reuse distance 2].
// 4 LDS slots x (A 16KB + B 16KB); stage tile t+3 during tile t (2+2 gloads);
// vmcnt(8) at tile top (peel 8/4/0 at 93/94/95). 2 phases x 16 MFMA, setprio.
#define TILE_STEP(T, STAGE, VMN)                                              \
  {                                                                           \
    const int slot_ = ((T) & 3) << 14;                                        \
    const int g3_ = (T) / 3, ph_ = (T) - 3 * g3_;                             \
    wait_vmcnt<VMN>();                                                        \
    __builtin_amdgcn_s_barrier();                                             \
    const int T3_ = (T) + 3;                                                  \
    const int s3_ = (T3_ & 3) << 14;                                          \
    const int h3_ = T3_ / 3, p3_ = T3_ - 3 * h3_;                             \
    if (STAGE){                                                               \
      const char* A3_ = Kblk + ((size_t)(p3_ == 1 ? h3_ + 32 : h3_) << 14);   \
      gload_lds16(A3_ + srcO0, &sh[s3_ + dstA0]);                             \
      gload_lds16(A3_ + srcO1, &sh[s3_ + dstA1]);                             \
    }                                                                         \
    (void)g3_; (void)ph_;                                                     \
    bf16x8 bh_[4], ah_[4];                                                    \
    _Pragma("unroll")                                                         \
    for (int nf = 0; nf < 4; ++nf)                                            \
      bh_[nf] = __builtin_bit_cast(bf16x8,                                    \
          *reinterpret_cast<const i32x4*>(&sh[slot_ + bidx[nf]]));            \
    _Pragma("unroll")                                                         \
    for (int mf = 0; mf < 4; ++mf)                                            \
      ah_[mf] = __builtin_bit_cast(bf16x8,                                    \
          *reinterpret_cast<const i32x4*>(&sh[slot_ + aidx[mf]]));            \
    __builtin_amdgcn_s_setprio(1);                                            \
    _Pragma("unroll")                                                         \
    for (int nf = 0; nf < 4; ++nf)                                            \
      _Pragma("unroll")                                                       \
      for (int mf = 0; mf < 4; ++mf)                                          \
        acc[mf][nf] = __builtin_amdgcn_mfma_f32_16x16x32_bf16(                \
            ah_[mf], bh_[nf], acc[mf][nf], 0, 0, 0);                          \
    __builtin_amdgcn_s_setprio(0);                                            \
    __builtin_amdgcn_s_barrier();                                             \
    if (STAGE){                                                               \
      const char* B3_ = Wblk + ((size_t)(p3_ == 2 ? h3_ + 32 : h3_) << 14);   \
      gload_lds16(B3_ + srcO0, &sh[s3_ + dstB0]);                             \
      gload_lds16(B3_ + srcO1, &sh[s3_ + dstB1]);                             \
    }                                                                         \
    _Pragma("unroll")                                                         \
    for (int mf = 0; mf < 4; ++mf)                                            \
      ah_[mf] = __builtin_bit_cast(bf16x8,                                    \
          *reinterpret_cast<const i32x4*>(&sh[slot_ + aidx[4 + mf]]));        \
    __builtin_amdgcn_s_setprio(1);                                            \
    _Pragma("unroll")                                                         \
    for (int nf = 0; nf < 4; ++nf)                                            \
      _Pragma("unroll")                                                       \
      for (int mf = 0; mf < 4; ++mf)                                          \
        acc[4 + mf][nf] = __builtin_amdgcn_mfma_f32_16x16x32_bf16(            \
            ah_[mf], bh_[nf], acc[4 + mf][nf], 0, 0, 0);                      \
    __builtin_amdgcn_s_setprio(0);                                            \
  }

__global__ __launch_bounds__(512, 2) void score8_kernel(
    const unsigned short* __restrict__ Ks,
    const unsigned short* __restrict__ Ws,
    const float* __restrict__ Vb,
    const float* __restrict__ vw,
    float* __restrict__ e_part)
{
  __shared__ __align__(16) unsigned short sh[65536];  // 4 slots x 32KB
  __shared__ float ebuf[4][256];

  const int t = threadIdx.x;
  const int w = t >> 6, l = t & 63;
  const int l15 = l & 15, lg = l >> 4;
  const int wr = w >> 2, wc = w & 3;

  // XCD-bijective swizzle: 4 N-chunks of one M-tile on one XCD.
  const int orig = blockIdx.x;
  const int xcd = orig & 7;
  const int s0 = orig >> 3;
  const int mtile = ((s0 >> 2) << 3) | xcd;   // [0,256)
  const int nchunk = s0 & 3;
  const int row0 = mtile << 8;
  const int nb0 = nchunk << 8;
  const int bb = row0 >> 11;

  const char* Kblk = (const char*)Ks + ((size_t)mtile << 20);
  const char* Wblk = (const char*)Ws + ((size_t)nchunk << 20);

  // fragment ds_read offsets (ushort, slot-relative), conflict-free layout
  int aidx[8], bidx[4];
  #pragma unroll
  for (int mf = 0; mf < 8; ++mf){
    int r = (wr << 7) + (mf << 4) + l15;
    aidx[mf] = ((r >> 1) << 6) + ((r & 1) << 5) + ((lg ^ ((r >> 1) & 3)) << 3);
  }
  #pragma unroll
  for (int nf = 0; nf < 4; ++nf){
    int r = (wc << 6) + (nf << 4) + l15;
    bidx[nf] = 8192 + ((r >> 1) << 6) + ((r & 1) << 5) + ((lg ^ ((r >> 1) & 3)) << 3);
  }

  // staging offsets: linear (global image layout == LDS layout)
  const int srcO0 = (w << 10) + (l << 4);   // bytes
  const int srcO1 = srcO0 + 8192;
  const int dstA0 = (w << 9) + (l << 3);    // ushorts
  const int dstA1 = dstA0 + 4096;
  const int dstB0 = dstA0 + 8192;
  const int dstB1 = dstA0 + 12288;

  f32x4 acc[8][4];
  #pragma unroll
  for (int mf = 0; mf < 8; ++mf)
    #pragma unroll
    for (int nf = 0; nf < 4; ++nf)
      acc[mf][nf] = (f32x4)0.0f;

  // prologue: stage tiles 0,1,2 into slots 0,1,2 (A imgs 0,32,0; B 0,0,32)
  #pragma unroll
  for (int pt = 0; pt < 3; ++pt){
    const char* Ai = Kblk + ((size_t)(pt == 1 ? 32 : 0) << 14);
    const char* Bi = Wblk + ((size_t)(pt == 2 ? 32 : 0) << 14);
    const int s = pt << 14;
    gload_lds16(Ai + srcO0, &sh[s + dstA0]);
    gload_lds16(Ai + srcO1, &sh[s + dstA1]);
    gload_lds16(Bi + srcO0, &sh[s + dstB0]);
    gload_lds16(Bi + srcO1, &sh[s + dstB1]);
  }

  #pragma unroll 1
  for (int T = 0; T < 93; ++T)
    TILE_STEP(T, true, 8);
  TILE_STEP(93, false, 8);
  TILE_STEP(94, false, 4);
  TILE_STEP(95, false, 0);

  // epilogue: partial e over this block's 256 N-cols
  float er[32];
  #pragma unroll
  for (int j2 = 0; j2 < 32; ++j2) er[j2] = 0.0f;
  #pragma unroll
  for (int nf = 0; nf < 4; ++nf){
    int n = nb0 + (wc << 6) + (nf << 4) + l15;
    float Vl  = Vb[bb * NA + n];
    float vwl = vw[n];
    #pragma unroll
    for (int mf = 0; mf < 8; ++mf)
      #pragma unroll
      for (int i = 0; i < 4; ++i)
        er[(mf << 2) + i] += tanh_fast(acc[mf][nf][i] + Vl) * vwl;
  }
  #pragma unroll
  for (int j2 = 0; j2 < 32; ++j2){
    #pragma unroll
    for (int off = 1; off < 16; off <<= 1)
      er[j2] += __shfl_xor(er[j2], off, 64);
  }
  if (l15 == 0){
    #pragma unroll
    for (int mf = 0; mf < 8; ++mf)
      #pragma unroll
      for (int i = 0; i < 4; ++i)
        ebuf[wc][(wr << 7) + (mf << 4) + (lg << 2) + i] = er[(mf << 2) + i];
  }
  __syncthreads();
  if (t < 256)
    e_part[(size_t)nchunk * MROWS + row0 + t] =
        ebuf[0][t] + ebuf[1][t] + ebuf[2][t] + ebuf[3][t];
}

// ---- kernel 3: sum partials + softmax over S --------------------------------
__global__ __launch_bounds__(256) void softmax_kernel(
    const float* __restrict__ e_part, float* __restrict__ a)
{
  __shared__ float red[4];
  const int b = blockIdx.x;
  const int t = threadIdx.x;
  const int l = t & 63, w = t >> 6;
  const float* ep = e_part + b * NS + t * 8;
  float v[8];
  #pragma unroll
  for (int j = 0; j < 8; ++j) v[j] = 0.0f;
  #pragma unroll
  for (int c = 0; c < 4; ++c){
    f32x4 x0 = *reinterpret_cast<const f32x4*>(ep + (size_t)c * MROWS);
    f32x4 x1 = *reinterpret_cast<const f32x4*>(ep + (size_t)c * MROWS + 4);
    #pragma unroll
    for (int j = 0; j < 4; ++j){ v[j] += x0[j]; v[4 + j] += x1[j]; }
  }

  float m = v[0];
  #pragma unroll
  for (int j = 1; j < 8; ++j) m = fmaxf(m, v[j]);
  #pragma unroll
  for (int off = 1; off < 64; off <<= 1) m = fmaxf(m, __shfl_xor(m, off, 64));
  if (l == 0) red[w] = m;
  __syncthreads();
  m = fmaxf(fmaxf(red[0], red[1]), fmaxf(red[2], red[3]));
  __syncthreads();

  float ex[8];
  float ssum = 0.0f;
  #pragma unroll
  for (int j = 0; j < 8; ++j){ ex[j] = __expf(v[j] - m); ssum += ex[j]; }
  #pragma unroll
  for (int off = 1; off < 64; off <<= 1) ssum += __shfl_xor(ssum, off, 64);
  if (l == 0) red[w] = ssum;
  __syncthreads();
  ssum = red[0] + red[1] + red[2] + red[3];
  float inv = 1.0f / ssum;

  float o[8];
  #pragma unroll
  for (int j = 0; j < 8; ++j) o[j] = ex[j] * inv;
  float* ap = a + b * NS + t * 8;
  *reinterpret_cast<f32x4*>(ap)     = *reinterpret_cast<f32x4*>(&o[0]);
  *reinterpret_cast<f32x4*>(ap + 4) = *reinterpret_cast<f32x4*>(&o[4]);
}

// ---- kernel 4a: partial context from swizzled hi images --------------------
__global__ __launch_bounds__(256) void ctx_partial_swz_kernel(
    const float* __restrict__ a, const unsigned short* __restrict__ Ks,
    float* __restrict__ part)
{
  const int bid = blockIdx.x;            // mtile 0..255 = b*8+sc
  const int t = threadIdx.x;             // e = t*4
  const int g = t >> 3;
  const int blk = (t >> 1) & 3;
  const int off8 = (t & 1) << 2;
  const size_t ibase = ((size_t)bid << 19) + ((size_t)g << 13) + off8;
  const float* ap = a + bid * 256;
  f32x4 accv = (f32x4)0.0f;
  for (int si = 0; si < 256; ++si){
    const int rp = si >> 1, c = si & 1;
    const size_t addr = ibase + (rp << 6) + (c << 5) + ((size_t)(blk ^ (rp & 3)) << 3);
    u16x4 k4 = *reinterpret_cast<const u16x4*>(Ks + addr);
    float as = ap[si];
    #pragma unroll
    for (int j = 0; j < 4; ++j) accv[j] += as * bf16_f32(k4[j]);
  }
  *reinterpret_cast<f32x4*>(part + (size_t)bid * NE + t * 4) = accv;
}

// ---- kernel 4b: deterministic reduce of partials ----------------------------
__global__ __launch_bounds__(256) void ctx_reduce_kernel(
    const float* __restrict__ part, float* __restrict__ out)
{
  const int b = blockIdx.x;
  const int t = threadIdx.x;
  f32x4 s = (f32x4)0.0f;
  #pragma unroll
  for (int sc = 0; sc < 8; ++sc)
    s += *reinterpret_cast<const f32x4*>(part + (size_t)((b << 3) + sc) * NE + t * 4);
  *reinterpret_cast<f32x4*>(out + b * NE + t * 4) = s;
}

extern "C" void kernel_launch(void* const* d_in, const int* in_sizes, int n_in,
                              void* d_out, int out_size, void* d_ws, size_t ws_size,
                              hipStream_t stream)
{
  const float* keys = (const float*)d_in[0];
  const float* q    = (const float*)d_in[1];
  const float* We   = (const float*)d_in[2];
  const float* Wd   = (const float*)d_in[3];
  const float* vw   = (const float*)d_in[4];
  float* out = (float*)d_out;

  char* ws = (char*)d_ws;
  const size_t MB = 1024 * 1024;
  unsigned short* Ws_img = (unsigned short*)(ws);               // 4 MB
  float* Vb     = (float*)(ws + 4 * MB);                        // 128 KB
  float* e_part = (float*)(ws + 4 * MB + 131072);               // 1 MB
  float* a      = (float*)(ws + 5 * MB + 131072);               // 256 KB
  unsigned short* Ks_img = (unsigned short*)(ws + 8 * MB);      // 256 MB
  float* part   = e_part;  // aliased: e_part dead after softmax

  split_swz_kernel<<<512,   256, 0, stream>>>(We,   Ws_img);
  split_swz_kernel<<<32768, 256, 0, stream>>>(keys, Ks_img);
  v_kernel<<<(NB * NA) / 4, 256, 0, stream>>>(q, Wd, Vb);
  score8_kernel<<<1024, 512, 0, stream>>>(Ks_img, Ws_img, Vb, vw, e_part);
  softmax_kernel<<<NB, 256, 0, stream>>>(e_part, a);
  ctx_partial_swz_kernel<<<NB * 8, 256, 0, stream>>>(a, Ks_img, part);
  ctx_reduce_kernel<<<NB, 256, 0, stream>>>(part, out);
}

// Round 6
// 557.815 us; speedup vs baseline: 1.2681x; 1.2681x over previous
//
#include <hip/hip_runtime.h>
#include <stdint.h>

#define NB 32
#define NS 2048
#define NE 1024   // ENC
#define ND 1024   // DEC
#define NA 1024   // ATT
#define MROWS (NB * NS)   // 65536

typedef float f32x4 __attribute__((ext_vector_type(4)));
typedef __bf16 bf16x8 __attribute__((ext_vector_type(8)));
typedef int i32x4 __attribute__((ext_vector_type(4)));
typedef unsigned short u16x4 __attribute__((ext_vector_type(4)));

typedef __attribute__((address_space(3))) unsigned int lds_u32;
typedef __attribute__((address_space(1))) unsigned int glb_u32;

__device__ __forceinline__ unsigned short f32_bf16(float x){
  unsigned int u = __float_as_uint(x);
  unsigned int r = (u + 0x7fffu + ((u >> 16) & 1u)) >> 16;
  return (unsigned short)r;
}
__device__ __forceinline__ float bf16_f32(unsigned short h){
  return __uint_as_float(((unsigned int)h) << 16);
}
__device__ __forceinline__ float tanh_fast(float x){
  float ax = fabsf(x);
  float e = __expf(-2.0f * ax);
  float t = (1.0f - e) * __builtin_amdgcn_rcpf(1.0f + e);
  return x < 0.0f ? -t : t;
}
__device__ __forceinline__ void gload_lds16(const void* g, void* l){
  __builtin_amdgcn_global_load_lds((const glb_u32*)g, (lds_u32*)l, 16, 0, 0);
}
__device__ __forceinline__ bf16x8 ldsrd(const void* p){
  return __builtin_bit_cast(bf16x8, *reinterpret_cast<const i32x4*>(p));
}

#define BARRIER() asm volatile("s_barrier" ::: "memory")
#define VMCNT(n)  asm volatile("s_waitcnt vmcnt(" #n ")" ::: "memory")

// virtual tile tau in [0,48): product g = tau/3, phase ph = tau%3
// products: ph0 = Ah*Bh, ph1 = Al*Bh, ph2 = Ah*Bl
__device__ __forceinline__ int imgA(int tau){ int g = tau / 3, ph = tau - 3 * g; return (ph == 1) ? 16 + g : g; }
__device__ __forceinline__ int imgB(int tau){ int g = tau / 3, ph = tau - 3 * g; return (ph == 2) ? 16 + g : g; }

// ---- kernel 0: split f32 rows -> swizzled bf16 hi/lo images ----------------
// Per 256-row mtile: 32 images of 32KB (g<16: hi of k[64g,64g+64); 16+g: lo).
// Image: half h = r>>7 (16KB), rl = r&127: byte = rl*128 + ((kb^(rl&7))<<4)
// + (k&7)*2, kb = in-image 16B-block (0..7). Equals the GEMM LDS tile layout,
// so global_load_lds staging is linear (rule #21 both-sides swizzle).
__global__ __launch_bounds__(256) void split_img_kernel(
    const float* __restrict__ src, unsigned short* __restrict__ dst)
{
  const size_t idx = (size_t)blockIdx.x * 256 + threadIdx.x;
  const int kbg = (int)(idx & 127);
  const size_t R = idx >> 7;
  const int m  = (int)(R >> 8);
  const int r  = (int)(R & 255);
  const int h  = r >> 7, rl = r & 127;
  const int g  = kbg >> 3, kb = kbg & 7;
  const float* sp = src + (R << 10) + (kbg << 3);
  f32x4 v0 = *reinterpret_cast<const f32x4*>(sp);
  f32x4 v1 = *reinterpret_cast<const f32x4*>(sp + 4);
  float f[8] = {v0[0], v0[1], v0[2], v0[3], v1[0], v1[1], v1[2], v1[3]};
  unsigned short hh[8], ll[8];
  #pragma unroll
  for (int j = 0; j < 8; ++j){
    hh[j] = f32_bf16(f[j]);
    ll[j] = f32_bf16(f[j] - bf16_f32(hh[j]));
  }
  i32x4 hp, lp;
  #pragma unroll
  for (int j = 0; j < 4; ++j){
    hp[j] = (int)((unsigned int)hh[2*j] | ((unsigned int)hh[2*j+1] << 16));
    lp[j] = (int)((unsigned int)ll[2*j] | ((unsigned int)ll[2*j+1] << 16));
  }
  const size_t base = ((size_t)m << 19) + ((size_t)g << 14) + ((size_t)h << 13)
                    + ((size_t)rl << 6) + ((size_t)((kb ^ (rl & 7)) << 3));
  *reinterpret_cast<i32x4*>(dst + base)                       = hp;
  *reinterpret_cast<i32x4*>(dst + base + ((size_t)16 << 14))  = lp;
}

// ---- kernel 1: V[b][a] = sum_d q[b][d]*W_d2a[a][d] -------------------------
__global__ __launch_bounds__(256) void v_kernel(
    const float* __restrict__ q, const float* __restrict__ Wd,
    float* __restrict__ V)
{
  int gw = blockIdx.x * 4 + (threadIdx.x >> 6);
  int l = threadIdx.x & 63;
  int b = gw >> 10, a = gw & 1023;
  const float* qp = q + b * ND;
  const float* wp = Wd + (size_t)a * ND;
  float s = 0.0f;
  #pragma unroll
  for (int c = 0; c < 4; ++c){
    int off = c * 256 + l * 4;
    f32x4 q4 = *reinterpret_cast<const f32x4*>(qp + off);
    f32x4 w4 = *reinterpret_cast<const f32x4*>(wp + off);
    s += q4[0]*w4[0] + q4[1]*w4[1] + q4[2]*w4[2] + q4[3]*w4[3];
  }
  #pragma unroll
  for (int off = 1; off < 64; off <<= 1) s += __shfl_xor(s, off, 64);
  if (l == 0) V[gw] = s;
}

// ---- kernel 2: 256x256 m201-style 8-phase GEMM, virtual K = 3072 -----------
// 24 iterations x 2 tiles x 4 quadrant-phases of 16 MFMA. One 16KB half-tile
// stage per phase (2 gload_lds/thread). RACE FIX vs R5: every counted VMCNT
// now sits BEFORE a barrier that precedes the dependent ds_reads (vmcnt is
// per-wave; cross-wave visibility needs vmcnt -> barrier -> read). vmcnt(4)
// at P4-end (covers A(o),B(o) read in P5) and P8-end (covers A(e+2),B(e+2)
// read at next P1); prologue drains A(0),B(0) with vmcnt(4)+barrier.
__global__ __launch_bounds__(512, 2) void score8p_kernel(
    const unsigned short* __restrict__ Ks,
    const unsigned short* __restrict__ Ws,
    const float* __restrict__ Vb,
    const float* __restrict__ vw,
    float* __restrict__ e_part)
{
  __shared__ __align__(16) unsigned char shb[131072];  // A: 4x16KB, B: 4x16KB
  __shared__ float ebuf[4][256];

  const int t = threadIdx.x;
  const int w = t >> 6, l = t & 63;
  const int l15 = l & 15, lg = l >> 4;
  const int wr = w >> 2, wc = w & 3;
  const int hb = wc >> 1;

  // XCD-bijective swizzle: 4 N-chunks of one M-tile on one XCD.
  const int orig = blockIdx.x;
  const int xcd = orig & 7;
  const int s0 = orig >> 3;
  const int mtile = ((s0 >> 2) << 3) | xcd;
  const int nchunk = s0 & 3;
  const int row0 = mtile << 8;
  const int nb0 = nchunk << 8;
  const int bb = row0 >> 11;

  const char* Kblk = (const char*)Ks + ((size_t)mtile << 20);
  const char* Wblk = (const char*)Ws + ((size_t)nchunk << 20);

  const int l15r = l15 << 7;
  const int c0  = (lg ^ (l15 & 7)) << 4;
  const int kt0 = c0, kt1 = c0 ^ 64;
  const int stoff = t << 4;

  // LDS byte bases. A slot(d, h=wr): ((d<<1)+wr)<<14. B: +65536, h=hb, +row64.
  const int Abase0 = (wr << 14);
  const int Abase1 = ((2 + wr) << 14);
  const int Bbase0 = 65536 + (hb << 14) + ((wc & 1) << 13);
  const int Bbase1 = 65536 + ((2 + hb) << 14) + ((wc & 1) << 13);

  f32x4 acc[8][4];
  #pragma unroll
  for (int mf = 0; mf < 8; ++mf)
    #pragma unroll
    for (int nf = 0; nf < 4; ++nf)
      acc[mf][nf] = (f32x4)0.0f;

  #define STAGE_(img, h, isA, d)                                               \
    { const char* s_ = (img) + ((h) << 14) + stoff;                            \
      unsigned char* d_ = shb + ((isA) ? 0 : 65536) + ((((d) << 1) + (h)) << 14) + stoff; \
      gload_lds16(s_, d_); gload_lds16(s_ + 8192, d_ + 8192); }

  #define RD_A(Ab, s, dstv)                                                    \
    { const unsigned char* p_ = shb + (Ab) + ((s) << 13) + l15r;               \
      _Pragma("unroll") for (int j_ = 0; j_ < 4; ++j_){                        \
        dstv[j_][0] = ldsrd(p_ + (j_ << 11) + kt0);                            \
        dstv[j_][1] = ldsrd(p_ + (j_ << 11) + kt1); } }

  #define RD_B(Bb, nh, dstv)                                                   \
    { const unsigned char* p_ = shb + (Bb) + ((nh) << 12) + l15r;              \
      _Pragma("unroll") for (int j_ = 0; j_ < 2; ++j_){                        \
        dstv[j_][0] = ldsrd(p_ + (j_ << 11) + kt0);                            \
        dstv[j_][1] = ldsrd(p_ + (j_ << 11) + kt1); } }

  #define MM_Q(MH, NH, A_, B_)                                                 \
    { __builtin_amdgcn_s_setprio(1);                                           \
      _Pragma("unroll") for (int jn_ = 0; jn_ < 2; ++jn_)                      \
        _Pragma("unroll") for (int j_ = 0; j_ < 4; ++j_){                      \
          acc[((MH)<<2)+j_][((NH)<<1)+jn_] = __builtin_amdgcn_mfma_f32_16x16x32_bf16( \
              A_[j_][0], B_[jn_][0], acc[((MH)<<2)+j_][((NH)<<1)+jn_], 0, 0, 0);      \
          acc[((MH)<<2)+j_][((NH)<<1)+jn_] = __builtin_amdgcn_mfma_f32_16x16x32_bf16( \
              A_[j_][1], B_[jn_][1], acc[((MH)<<2)+j_][((NH)<<1)+jn_], 0, 0, 0); }    \
      __builtin_amdgcn_s_setprio(0); }

  bf16x8 aA[4][2], bB0[2][2], bB1[2][2];

  auto iter = [&](int i, bool last){
    const int e = i << 1, o = e | 1;
    const int e2 = (e + 2 > 47) ? 0 : e + 2;
    const int o2 = (o + 2 > 47) ? 0 : o + 2;
    const char* pAo  = Kblk + ((size_t)imgA(o)  << 15);
    const char* pBe2 = Wblk + ((size_t)imgB(e2) << 15);
    const char* pAe2 = Kblk + ((size_t)imgA(e2) << 15);
    const char* pBo2 = Wblk + ((size_t)imgB(o2) << 15);
    // P1: A(e),B(e) already vmcnt+barrier-guaranteed; stage A(o)h0 -> dbuf1
    RD_A(Abase0, 0, aA); RD_B(Bbase0, 0, bB0);
    STAGE_(pAo, 0, 1, 1);
    BARRIER(); MM_Q(0, 0, aA, bB0); BARRIER();
    // P2
    RD_B(Bbase0, 1, bB1);
    STAGE_(pAo, 1, 1, 1);
    BARRIER(); MM_Q(0, 1, aA, bB1); BARRIER();
    // P3: B(e) fully read -> stage B(e+2) into dbuf0
    RD_A(Abase0, 1, aA);
    if (!last) STAGE_(pBe2, 0, 0, 0);
    BARRIER(); MM_Q(1, 0, aA, bB0); BARRIER();
    // P4: drain A(o),B(o) (oldest 8) BEFORE the barrier P5's reads follow
    if (!last) STAGE_(pBe2, 1, 0, 0);
    BARRIER(); MM_Q(1, 1, aA, bB1);
    if (last) { VMCNT(0); } else { VMCNT(4); }
    BARRIER();
    // P5: read A(o),B(o); stage A(e+2) into dbuf0
    RD_A(Abase1, 0, aA); RD_B(Bbase1, 0, bB0);
    if (!last) STAGE_(pAe2, 0, 1, 0);
    BARRIER(); MM_Q(0, 0, aA, bB0); BARRIER();
    // P6
    RD_B(Bbase1, 1, bB1);
    if (!last) STAGE_(pAe2, 1, 1, 0);
    BARRIER(); MM_Q(0, 1, aA, bB1); BARRIER();
    // P7: B(o) fully read -> stage B(o+2) into dbuf1
    RD_A(Abase1, 1, aA);
    if (!last) STAGE_(pBo2, 0, 0, 1);
    BARRIER(); MM_Q(1, 0, aA, bB0); BARRIER();
    // P8: drain A(e+2),B(e+2) before barrier; next P1 reads them
    if (!last) STAGE_(pBo2, 1, 0, 1);
    BARRIER(); MM_Q(1, 1, aA, bB1);
    if (!last) VMCNT(4);
    BARRIER();
  };

  // prologue: B(0)->d0, A(0)->d0, B(1)->d1  (imgA(0)=imgB(0)=imgB(1)=0)
  STAGE_(Wblk, 0, 0, 0); STAGE_(Wblk, 1, 0, 0);
  STAGE_(Kblk, 0, 1, 0); STAGE_(Kblk, 1, 1, 0);
  STAGE_(Wblk, 0, 0, 1); STAGE_(Wblk, 1, 0, 1);
  VMCNT(4);      // drain A(0),B(0) (oldest 8 of 12)
  BARRIER();     // ...for ALL waves, before any P1 read

  #pragma unroll 1
  for (int i = 0; i < 23; ++i) iter(i, false);
  iter(23, true);

  // epilogue: partial e over this block's 256 N-cols
  float er[32];
  #pragma unroll
  for (int j2 = 0; j2 < 32; ++j2) er[j2] = 0.0f;
  #pragma unroll
  for (int nf = 0; nf < 4; ++nf){
    int n = nb0 + (wc << 6) + (nf << 4) + l15;
    float Vl  = Vb[bb * NA + n];
    float vwl = vw[n];
    #pragma unroll
    for (int mf = 0; mf < 8; ++mf)
      #pragma unroll
      for (int i = 0; i < 4; ++i)
        er[(mf << 2) + i] += tanh_fast(acc[mf][nf][i] + Vl) * vwl;
  }
  #pragma unroll
  for (int j2 = 0; j2 < 32; ++j2){
    #pragma unroll
    for (int off = 1; off < 16; off <<= 1)
      er[j2] += __shfl_xor(er[j2], off, 64);
  }
  if (l15 == 0){
    #pragma unroll
    for (int mf = 0; mf < 8; ++mf)
      #pragma unroll
      for (int i = 0; i < 4; ++i)
        ebuf[wc][(wr << 7) + (mf << 4) + (lg << 2) + i] = er[(mf << 2) + i];
  }
  __syncthreads();
  if (t < 256)
    e_part[(size_t)nchunk * MROWS + row0 + t] =
        ebuf[0][t] + ebuf[1][t] + ebuf[2][t] + ebuf[3][t];
  #undef STAGE_
  #undef RD_A
  #undef RD_B
  #undef MM_Q
}

// ---- kernel 3: sum 4 partials + softmax over S ------------------------------
__global__ __launch_bounds__(256) void softmax_kernel(
    const float* __restrict__ e_part, float* __restrict__ a)
{
  __shared__ float red[4];
  const int b = blockIdx.x;
  const int t = threadIdx.x;
  const int l = t & 63, w = t >> 6;
  const float* ep = e_part + b * NS + t * 8;
  float v[8];
  #pragma unroll
  for (int j = 0; j < 8; ++j) v[j] = 0.0f;
  #pragma unroll
  for (int c = 0; c < 4; ++c){
    f32x4 x0 = *reinterpret_cast<const f32x4*>(ep + (size_t)c * MROWS);
    f32x4 x1 = *reinterpret_cast<const f32x4*>(ep + (size_t)c * MROWS + 4);
    #pragma unroll
    for (int j = 0; j < 4; ++j){ v[j] += x0[j]; v[4 + j] += x1[j]; }
  }

  float m = v[0];
  #pragma unroll
  for (int j = 1; j < 8; ++j) m = fmaxf(m, v[j]);
  #pragma unroll
  for (int off = 1; off < 64; off <<= 1) m = fmaxf(m, __shfl_xor(m, off, 64));
  if (l == 0) red[w] = m;
  __syncthreads();
  m = fmaxf(fmaxf(red[0], red[1]), fmaxf(red[2], red[3]));
  __syncthreads();

  float ex[8];
  float ssum = 0.0f;
  #pragma unroll
  for (int j = 0; j < 8; ++j){ ex[j] = __expf(v[j] - m); ssum += ex[j]; }
  #pragma unroll
  for (int off = 1; off < 64; off <<= 1) ssum += __shfl_xor(ssum, off, 64);
  if (l == 0) red[w] = ssum;
  __syncthreads();
  ssum = red[0] + red[1] + red[2] + red[3];
  float inv = 1.0f / ssum;

  float o[8];
  #pragma unroll
  for (int j = 0; j < 8; ++j) o[j] = ex[j] * inv;
  float* ap = a + b * NS + t * 8;
  *reinterpret_cast<f32x4*>(ap)     = *reinterpret_cast<f32x4*>(&o[0]);
  *reinterpret_cast<f32x4*>(ap + 4) = *reinterpret_cast<f32x4*>(&o[4]);
}

// ---- kernel 4a: partial context from swizzled hi images --------------------
__global__ __launch_bounds__(256) void ctx_partial_swz_kernel(
    const float* __restrict__ a, const unsigned short* __restrict__ Ks,
    float* __restrict__ part)
{
  const int bid = blockIdx.x;            // mtile 0..255 = b*8+sc
  const int t = threadIdx.x;             // covers e-cols [t*4, t*4+4)
  const int g = t >> 4;                  // k-image
  const int kb = (t >> 1) & 7;           // 16B block within image row
  const size_t ibase = ((size_t)bid << 19) + ((size_t)g << 14) + ((size_t)(t & 1) << 2);
  const float* ap = a + bid * 256;
  f32x4 accv = (f32x4)0.0f;
  for (int si = 0; si < 256; ++si){
    const int h = si >> 7, rl = si & 127;
    const size_t addr = ibase + ((size_t)h << 13) + ((size_t)rl << 6)
                      + ((size_t)((kb ^ (rl & 7)) << 3));
    u16x4 k4 = *reinterpret_cast<const u16x4*>(Ks + addr);
    float as = ap[si];
    #pragma unroll
    for (int j = 0; j < 4; ++j) accv[j] += as * bf16_f32(k4[j]);
  }
  *reinterpret_cast<f32x4*>(part + (size_t)bid * NE + t * 4) = accv;
}

// ---- kernel 4b: deterministic reduce of partials ----------------------------
__global__ __launch_bounds__(256) void ctx_reduce_kernel(
    const float* __restrict__ part, float* __restrict__ out)
{
  const int b = blockIdx.x;
  const int t = threadIdx.x;
  f32x4 s = (f32x4)0.0f;
  #pragma unroll
  for (int sc = 0; sc < 8; ++sc)
    s += *reinterpret_cast<const f32x4*>(part + (size_t)((b << 3) + sc) * NE + t * 4);
  *reinterpret_cast<f32x4*>(out + b * NE + t * 4) = s;
}

extern "C" void kernel_launch(void* const* d_in, const int* in_sizes, int n_in,
                              void* d_out, int out_size, void* d_ws, size_t ws_size,
                              hipStream_t stream)
{
  const float* keys = (const float*)d_in[0];
  const float* q    = (const float*)d_in[1];
  const float* We   = (const float*)d_in[2];
  const float* Wd   = (const float*)d_in[3];
  const float* vw   = (const float*)d_in[4];
  float* out = (float*)d_out;

  char* ws = (char*)d_ws;
  const size_t MB = 1024 * 1024;
  unsigned short* Ws_img = (unsigned short*)(ws);               // 4 MB
  float* Vb     = (float*)(ws + 4 * MB);                        // 128 KB
  float* e_part = (float*)(ws + 4 * MB + 131072);               // 1 MB
  float* a      = (float*)(ws + 5 * MB + 131072);               // 256 KB
  unsigned short* Ks_img = (unsigned short*)(ws + 8 * MB);      // 256 MB
  float* part   = e_part;  // aliased: e_part dead after softmax

  split_img_kernel<<<512,   256, 0, stream>>>(We,   Ws_img);
  split_img_kernel<<<32768, 256, 0, stream>>>(keys, Ks_img);
  v_kernel<<<(NB * NA) / 4, 256, 0, stream>>>(q, Wd, Vb);
  score8p_kernel<<<1024, 512, 0, stream>>>(Ks_img, Ws_img, Vb, vw, e_part);
  softmax_kernel<<<NB, 256, 0, stream>>>(e_part, a);
  ctx_partial_swz_kernel<<<NB * 8, 256, 0, stream>>>(a, Ks_img, part);
  ctx_reduce_kernel<<<NB, 256, 0, stream>>>(part, out);
}

// Round 7
// 476.433 us; speedup vs baseline: 1.4847x; 1.1708x over previous
//
#include <hip/hip_runtime.h>
#include <stdint.h>

#define NB 32
#define NS 2048
#define NE 1024   // ENC
#define ND 1024   // DEC
#define NA 1024   // ATT
#define MROWS (NB * NS)   // 65536

typedef float f32x4 __attribute__((ext_vector_type(4)));
typedef __bf16 bf16x8 __attribute__((ext_vector_type(8)));
typedef int i32x4 __attribute__((ext_vector_type(4)));
typedef unsigned short u16x4 __attribute__((ext_vector_type(4)));

typedef __attribute__((address_space(3))) unsigned int lds_u32;
typedef __attribute__((address_space(1))) unsigned int glb_u32;

__device__ __forceinline__ unsigned short f32_bf16(float x){
  unsigned int u = __float_as_uint(x);
  unsigned int r = (u + 0x7fffu + ((u >> 16) & 1u)) >> 16;
  return (unsigned short)r;
}
__device__ __forceinline__ float bf16_f32(unsigned short h){
  return __uint_as_float(((unsigned int)h) << 16);
}
__device__ __forceinline__ float tanh_fast(float x){
  float ax = fabsf(x);
  float e = __expf(-2.0f * ax);
  float t = (1.0f - e) * __builtin_amdgcn_rcpf(1.0f + e);
  return x < 0.0f ? -t : t;
}
__device__ __forceinline__ void gload_lds16(const void* g, void* l){
  __builtin_amdgcn_global_load_lds((const glb_u32*)g, (lds_u32*)l, 16, 0, 0);
}
__device__ __forceinline__ bf16x8 ldsrd(const void* p){
  return __builtin_bit_cast(bf16x8, *reinterpret_cast<const i32x4*>(p));
}

#define BARRIER() asm volatile("s_barrier" ::: "memory")
#define VMCNT0()  asm volatile("s_waitcnt vmcnt(0)" ::: "memory")

// ---- kernel 0: split f32 -> grouped swizzled bf16 images -------------------
// Per 256-row tile m (1 MB): hi images g=0..31 (16 KB = rows x k[32g,32g+32))
// at m*1MB + g*16KB; lo images at +512KB. Within image (ushort offsets):
// off = r*32 + ((kb ^ ((r>>1)&3))*8 + (k&7), kb=(k>>3)&3. The swizzle makes
// quarter-wave ds_read_b128 2-way max (free); staging is linear (rule #21).
__global__ __launch_bounds__(256) void split_img_kernel(
    const float* __restrict__ src, unsigned short* __restrict__ dst)
{
  const size_t idx = (size_t)blockIdx.x * 256 + threadIdx.x;
  const int kbg = (int)(idx & 127);    // e>>3
  const size_t R = idx >> 7;
  const int m  = (int)(R >> 8);
  const int r  = (int)(R & 255);
  const int g  = kbg >> 2;
  const int kb = kbg & 3;
  const float* sp = src + (R << 10) + (kbg << 3);
  f32x4 v0 = *reinterpret_cast<const f32x4*>(sp);
  f32x4 v1 = *reinterpret_cast<const f32x4*>(sp + 4);
  float f[8] = {v0[0], v0[1], v0[2], v0[3], v1[0], v1[1], v1[2], v1[3]};
  unsigned short hh[8], ll[8];
  #pragma unroll
  for (int j = 0; j < 8; ++j){
    hh[j] = f32_bf16(f[j]);
    ll[j] = f32_bf16(f[j] - bf16_f32(hh[j]));
  }
  i32x4 hp, lp;
  #pragma unroll
  for (int j = 0; j < 4; ++j){
    hp[j] = (int)((unsigned int)hh[2*j] | ((unsigned int)hh[2*j+1] << 16));
    lp[j] = (int)((unsigned int)ll[2*j] | ((unsigned int)ll[2*j+1] << 16));
  }
  const size_t base = ((size_t)m << 19) + ((size_t)g << 13)
                    + ((size_t)r << 5) + (size_t)((kb ^ ((r >> 1) & 3)) << 3);
  *reinterpret_cast<i32x4*>(dst + base)          = hp;
  *reinterpret_cast<i32x4*>(dst + base + 262144) = lp;   // lo block (+512KB)
}

// ---- kernel 1: V[b][a] = sum_d q[b][d]*W_d2a[a][d] -------------------------
__global__ __launch_bounds__(256) void v_kernel(
    const float* __restrict__ q, const float* __restrict__ Wd,
    float* __restrict__ V)
{
  int gw = blockIdx.x * 4 + (threadIdx.x >> 6);
  int l = threadIdx.x & 63;
  int b = gw >> 10, a = gw & 1023;
  const float* qp = q + b * ND;
  const float* wp = Wd + (size_t)a * ND;
  float s = 0.0f;
  #pragma unroll
  for (int c = 0; c < 4; ++c){
    int off = c * 256 + l * 4;
    f32x4 q4 = *reinterpret_cast<const f32x4*>(qp + off);
    f32x4 w4 = *reinterpret_cast<const f32x4*>(wp + off);
    s += q4[0]*w4[0] + q4[1]*w4[1] + q4[2]*w4[2] + q4[3]*w4[3];
  }
  #pragma unroll
  for (int off = 1; off < 64; off <<= 1) s += __shfl_xor(s, off, 64);
  if (l == 0) V[gw] = s;
}

// ---- kernel 2: grouped-product GEMM, one barrier per K=32 group ------------
// 256x256 tile, 8 waves (2M x 4N), per-wave 128x64, acc[8][4]. 32 K-groups;
// per group: stage g+1 (8 gload_lds, 64 KB), then {Ah,Bh read once ->
// Ah*Bh, Al*Bh, Ah*Bl = 96 MFMA from 24 ds_read_b128}, then vmcnt(0)+barrier.
// No intra-group barriers: waves drift, LDS bursts overlap MFMA bursts.
__global__ __launch_bounds__(512, 2) void score_grp_kernel(
    const unsigned short* __restrict__ Ks,
    const unsigned short* __restrict__ Ws,
    const float* __restrict__ Vb,
    const float* __restrict__ vw,
    float* __restrict__ e_part)
{
  __shared__ __align__(16) unsigned char shb[131072];  // 2 bufs x 64 KB
  __shared__ float ebuf[4][256];

  const int t = threadIdx.x;
  const int w = t >> 6, l = t & 63;
  const int l15 = l & 15, lg = l >> 4;
  const int wr = w >> 2, wc = w & 3;

  // XCD-bijective swizzle: 4 N-chunks of one M-tile on one XCD.
  const int orig = blockIdx.x;
  const int xcd = orig & 7;
  const int s0 = orig >> 3;
  const int mtile = ((s0 >> 2) << 3) | xcd;
  const int nchunk = s0 & 3;
  const int row0 = mtile << 8;
  const int nb0 = nchunk << 8;
  const int bb = row0 >> 11;

  const char* Kblk = (const char*)Ks + ((size_t)mtile << 20);
  const char* Wblk = (const char*)Ws + ((size_t)nchunk << 20);

  // lane-constant ds_read bases (bytes): row*64 + swizzled 16B block
  const int swz = (lg ^ ((l15 >> 1) & 3)) << 4;
  const int vA0 = (((wr << 7) + l15) << 6) + swz;           // Ah (buf-rel)
  const int vB0 = 32768 + (((wc << 6) + l15) << 6) + swz;   // Bh (buf-rel)
  const int stoff = t << 4;

  f32x4 acc[8][4];
  #pragma unroll
  for (int mf = 0; mf < 8; ++mf)
    #pragma unroll
    for (int nf = 0; nf < 4; ++nf)
      acc[mf][nf] = (f32x4)0.0f;

  // stage all 4 images of group g1 into buffer bufW (8 gload_lds/thread)
  auto stage8 = [&](int g1, int bufW){
    const char* Ah = Kblk + (g1 << 14);
    const char* Bh = Wblk + (g1 << 14);
    unsigned char* d = shb + bufW;
    gload_lds16(Ah + stoff,          d + stoff);            // Ah -> +0
    gload_lds16(Ah + 8192 + stoff,   d + 8192 + stoff);
    gload_lds16(Ah + 524288 + stoff, d + 16384 + stoff);    // Al -> +16K
    gload_lds16(Ah + 532480 + stoff, d + 24576 + stoff);
    gload_lds16(Bh + stoff,          d + 32768 + stoff);    // Bh -> +32K
    gload_lds16(Bh + 8192 + stoff,   d + 40960 + stoff);
    gload_lds16(Bh + 524288 + stoff, d + 49152 + stoff);    // Bl -> +48K
    gload_lds16(Bh + 532480 + stoff, d + 57344 + stoff);
  };

  auto body = [&](int g, int bufR, int bufW){
    if (g < 31) stage8(g + 1, bufW);
    const unsigned char* pA = shb + bufR + vA0;
    const unsigned char* pB = shb + bufR + vB0;
    bf16x8 Ah[8], Bh[4], Al[8], Bl[4];
    #pragma unroll
    for (int mf = 0; mf < 8; ++mf) Ah[mf] = ldsrd(pA + mf * 1024);
    #pragma unroll
    for (int nf = 0; nf < 4; ++nf) Bh[nf] = ldsrd(pB + nf * 1024);
    __builtin_amdgcn_s_setprio(1);
    #pragma unroll
    for (int nf = 0; nf < 4; ++nf)
      #pragma unroll
      for (int mf = 0; mf < 8; ++mf)
        acc[mf][nf] = __builtin_amdgcn_mfma_f32_16x16x32_bf16(Ah[mf], Bh[nf], acc[mf][nf], 0, 0, 0);
    __builtin_amdgcn_s_setprio(0);
    #pragma unroll
    for (int mf = 0; mf < 8; ++mf) Al[mf] = ldsrd(pA + 16384 + mf * 1024);
    __builtin_amdgcn_s_setprio(1);
    #pragma unroll
    for (int nf = 0; nf < 4; ++nf)
      #pragma unroll
      for (int mf = 0; mf < 8; ++mf)
        acc[mf][nf] = __builtin_amdgcn_mfma_f32_16x16x32_bf16(Al[mf], Bh[nf], acc[mf][nf], 0, 0, 0);
    __builtin_amdgcn_s_setprio(0);
    #pragma unroll
    for (int nf = 0; nf < 4; ++nf) Bl[nf] = ldsrd(pB + 16384 + nf * 1024);
    __builtin_amdgcn_s_setprio(1);
    #pragma unroll
    for (int nf = 0; nf < 4; ++nf)
      #pragma unroll
      for (int mf = 0; mf < 8; ++mf)
        acc[mf][nf] = __builtin_amdgcn_mfma_f32_16x16x32_bf16(Ah[mf], Bl[nf], acc[mf][nf], 0, 0, 0);
    __builtin_amdgcn_s_setprio(0);
    VMCNT0();     // drains this wave's g+1 staging (issued ~whole group ago)
    BARRIER();    // all waves' staging visible; buffers swap safely
  };

  // prologue: stage group 0 into buf0, drain, sync
  stage8(0, 0);
  VMCNT0();
  BARRIER();

  #pragma unroll 1
  for (int gg = 0; gg < 16; ++gg){
    body(2 * gg,     0,     65536);
    body(2 * gg + 1, 65536, 0);
  }

  // epilogue: partial e over this block's 256 N-cols
  float er[32];
  #pragma unroll
  for (int j2 = 0; j2 < 32; ++j2) er[j2] = 0.0f;
  #pragma unroll
  for (int nf = 0; nf < 4; ++nf){
    int n = nb0 + (wc << 6) + (nf << 4) + l15;
    float Vl  = Vb[bb * NA + n];
    float vwl = vw[n];
    #pragma unroll
    for (int mf = 0; mf < 8; ++mf)
      #pragma unroll
      for (int i = 0; i < 4; ++i)
        er[(mf << 2) + i] += tanh_fast(acc[mf][nf][i] + Vl) * vwl;
  }
  #pragma unroll
  for (int j2 = 0; j2 < 32; ++j2){
    #pragma unroll
    for (int off = 1; off < 16; off <<= 1)
      er[j2] += __shfl_xor(er[j2], off, 64);
  }
  if (l15 == 0){
    #pragma unroll
    for (int mf = 0; mf < 8; ++mf)
      #pragma unroll
      for (int i = 0; i < 4; ++i)
        ebuf[wc][(wr << 7) + (mf << 4) + (lg << 2) + i] = er[(mf << 2) + i];
  }
  __syncthreads();
  if (t < 256)
    e_part[(size_t)nchunk * MROWS + row0 + t] =
        ebuf[0][t] + ebuf[1][t] + ebuf[2][t] + ebuf[3][t];
}

// ---- kernel 3: sum 4 partials + softmax over S ------------------------------
__global__ __launch_bounds__(256) void softmax_kernel(
    const float* __restrict__ e_part, float* __restrict__ a)
{
  __shared__ float red[4];
  const int b = blockIdx.x;
  const int t = threadIdx.x;
  const int l = t & 63, w = t >> 6;
  const float* ep = e_part + b * NS + t * 8;
  float v[8];
  #pragma unroll
  for (int j = 0; j < 8; ++j) v[j] = 0.0f;
  #pragma unroll
  for (int c = 0; c < 4; ++c){
    f32x4 x0 = *reinterpret_cast<const f32x4*>(ep + (size_t)c * MROWS);
    f32x4 x1 = *reinterpret_cast<const f32x4*>(ep + (size_t)c * MROWS + 4);
    #pragma unroll
    for (int j = 0; j < 4; ++j){ v[j] += x0[j]; v[4 + j] += x1[j]; }
  }

  float m = v[0];
  #pragma unroll
  for (int j = 1; j < 8; ++j) m = fmaxf(m, v[j]);
  #pragma unroll
  for (int off = 1; off < 64; off <<= 1) m = fmaxf(m, __shfl_xor(m, off, 64));
  if (l == 0) red[w] = m;
  __syncthreads();
  m = fmaxf(fmaxf(red[0], red[1]), fmaxf(red[2], red[3]));
  __syncthreads();

  float ex[8];
  float ssum = 0.0f;
  #pragma unroll
  for (int j = 0; j < 8; ++j){ ex[j] = __expf(v[j] - m); ssum += ex[j]; }
  #pragma unroll
  for (int off = 1; off < 64; off <<= 1) ssum += __shfl_xor(ssum, off, 64);
  if (l == 0) red[w] = ssum;
  __syncthreads();
  ssum = red[0] + red[1] + red[2] + red[3];
  float inv = 1.0f / ssum;

  float o[8];
  #pragma unroll
  for (int j = 0; j < 8; ++j) o[j] = ex[j] * inv;
  float* ap = a + b * NS + t * 8;
  *reinterpret_cast<f32x4*>(ap)     = *reinterpret_cast<f32x4*>(&o[0]);
  *reinterpret_cast<f32x4*>(ap + 4) = *reinterpret_cast<f32x4*>(&o[4]);
}

// ---- kernel 4a: partial context from grouped hi images ---------------------
__global__ __launch_bounds__(256) void ctx_partial_swz_kernel(
    const float* __restrict__ a, const unsigned short* __restrict__ Ks,
    float* __restrict__ part)
{
  const int bid = blockIdx.x;            // tile 0..255 = b*8+sc
  const int t = threadIdx.x;             // covers e-cols [t*4, t*4+4)
  const int g = t >> 3;                  // k-group image
  const int kb = (t >> 1) & 3;           // 16B block within image row
  const size_t ibase = ((size_t)bid << 19) + ((size_t)g << 13) + ((size_t)(t & 1) << 2);
  const float* ap = a + bid * 256;
  f32x4 accv = (f32x4)0.0f;
  for (int si = 0; si < 256; ++si){
    const size_t addr = ibase + ((size_t)si << 5)
                      + (size_t)((kb ^ ((si >> 1) & 3)) << 3);
    u16x4 k4 = *reinterpret_cast<const u16x4*>(Ks + addr);
    float as = ap[si];
    #pragma unroll
    for (int j = 0; j < 4; ++j) accv[j] += as * bf16_f32(k4[j]);
  }
  *reinterpret_cast<f32x4*>(part + (size_t)bid * NE + t * 4) = accv;
}

// ---- kernel 4b: deterministic reduce of partials ----------------------------
__global__ __launch_bounds__(256) void ctx_reduce_kernel(
    const float* __restrict__ part, float* __restrict__ out)
{
  const int b = blockIdx.x;
  const int t = threadIdx.x;
  f32x4 s = (f32x4)0.0f;
  #pragma unroll
  for (int sc = 0; sc < 8; ++sc)
    s += *reinterpret_cast<const f32x4*>(part + (size_t)((b << 3) + sc) * NE + t * 4);
  *reinterpret_cast<f32x4*>(out + b * NE + t * 4) = s;
}

extern "C" void kernel_launch(void* const* d_in, const int* in_sizes, int n_in,
                              void* d_out, int out_size, void* d_ws, size_t ws_size,
                              hipStream_t stream)
{
  const float* keys = (const float*)d_in[0];
  const float* q    = (const float*)d_in[1];
  const float* We   = (const float*)d_in[2];
  const float* Wd   = (const float*)d_in[3];
  const float* vw   = (const float*)d_in[4];
  float* out = (float*)d_out;

  char* ws = (char*)d_ws;
  const size_t MB = 1024 * 1024;
  unsigned short* Ws_img = (unsigned short*)(ws);               // 4 MB
  float* Vb     = (float*)(ws + 4 * MB);                        // 128 KB
  float* e_part = (float*)(ws + 4 * MB + 131072);               // 1 MB
  float* a      = (float*)(ws + 5 * MB + 131072);               // 256 KB
  unsigned short* Ks_img = (unsigned short*)(ws + 8 * MB);      // 256 MB
  float* part   = e_part;  // aliased: e_part dead after softmax

  split_img_kernel<<<512,   256, 0, stream>>>(We,   Ws_img);
  split_img_kernel<<<32768, 256, 0, stream>>>(keys, Ks_img);
  v_kernel<<<(NB * NA) / 4, 256, 0, stream>>>(q, Wd, Vb);
  score_grp_kernel<<<1024, 512, 0, stream>>>(Ks_img, Ws_img, Vb, vw, e_part);
  softmax_kernel<<<NB, 256, 0, stream>>>(e_part, a);
  ctx_partial_swz_kernel<<<NB * 8, 256, 0, stream>>>(a, Ks_img, part);
  ctx_reduce_kernel<<<NB, 256, 0, stream>>>(part, out);
}

// Round 8
// 366.443 us; speedup vs baseline: 1.9304x; 1.3002x over previous
//
#include <hip/hip_runtime.h>
#include <stdint.h>

#define NB 32
#define NS 2048
#define NE 1024   // ENC
#define ND 1024   // DEC
#define NA 1024   // ATT
#define MROWS (NB * NS)   // 65536

typedef float f32x4 __attribute__((ext_vector_type(4)));
typedef int i32x4 __attribute__((ext_vector_type(4)));

typedef __attribute__((address_space(3))) unsigned int lds_u32;
typedef __attribute__((address_space(1))) unsigned int glb_u32;

__device__ __forceinline__ float tanh_fast(float x){
  float ax = fabsf(x);
  float e = __expf(-2.0f * ax);
  float t = (1.0f - e) * __builtin_amdgcn_rcpf(1.0f + e);
  return x < 0.0f ? -t : t;
}
__device__ __forceinline__ void gload_lds16(const void* g, void* l){
  __builtin_amdgcn_global_load_lds((const glb_u32*)g, (lds_u32*)l, 16, 0, 0);
}

#define BARRIER() asm volatile("s_barrier" ::: "memory")
#define VMCNT0()  asm volatile("s_waitcnt vmcnt(0)" ::: "memory")

// ---- kernel 0: per-row i8-pair quantize into swizzled group images ---------
// x = s*(h + l/256), s = rowmax/126. Image layout per 256-row mtile (256 KB):
// 16 group-images (16 KB = K=64 x 256 rows); row pair rp = r>>1, c = r&1,
// granule = (c<<2)|(kb ^ (rp&3)), kb = k-block-of-16 within group. Both A and
// B use this identical lane->k packing, so any internal MFMA k-permutation
// cancels. 2-way bank aliasing max (free). Staging stays linear (rule #21).
// One wave per row; grid = rows/4, 256 threads.
__global__ __launch_bounds__(256) void quant_kernel(
    const float* __restrict__ src, unsigned char* __restrict__ dh,
    unsigned char* __restrict__ dl, float* __restrict__ sdst)
{
  const int t = threadIdx.x;
  const int w = t >> 6, l = t & 63;
  const int row = blockIdx.x * 4 + w;
  const float* sp = src + (size_t)row * 1024;

  f32x4 x[4];
  #pragma unroll
  for (int c = 0; c < 4; ++c)
    x[c] = *reinterpret_cast<const f32x4*>(sp + c * 256 + l * 4);

  float m = 0.0f;
  #pragma unroll
  for (int c = 0; c < 4; ++c)
    #pragma unroll
    for (int j = 0; j < 4; ++j) m = fmaxf(m, fabsf(x[c][j]));
  #pragma unroll
  for (int off = 1; off < 64; off <<= 1) m = fmaxf(m, __shfl_xor(m, off, 64));
  m = fmaxf(m, 1e-30f);
  const float s = m * (1.0f / 126.0f);
  const float inv = 126.0f / m;

  const int r = row & 255;
  const int rp = r >> 1, cc = r & 1;
  const int kb = (l >> 2) & 3;
  const int gran = (cc << 2) | (kb ^ (rp & 3));
  const size_t base = ((size_t)(row >> 8) << 18) + ((size_t)rp << 7)
                    + ((size_t)gran << 4) + ((l & 3) << 2);

  #pragma unroll
  for (int c = 0; c < 4; ++c){
    int hw = 0, lw = 0;
    #pragma unroll
    for (int j = 0; j < 4; ++j){
      float f = x[c][j] * inv;
      float hf = rintf(f);
      float lf = fminf(rintf((f - hf) * 256.0f), 127.0f);
      hw |= (((int)hf) & 255) << (8 * j);
      lw |= (((int)lf) & 255) << (8 * j);
    }
    const int g = c * 4 + (l >> 4);
    *reinterpret_cast<int*>(dh + base + ((size_t)g << 14)) = hw;
    *reinterpret_cast<int*>(dl + base + ((size_t)g << 14)) = lw;
  }
  if (l == 0) sdst[row] = s;
}

// ---- kernel 1: V[b][a] = sum_d q[b][d]*W_d2a[a][d] -------------------------
__global__ __launch_bounds__(256) void v_kernel(
    const float* __restrict__ q, const float* __restrict__ Wd,
    float* __restrict__ V)
{
  int gw = blockIdx.x * 4 + (threadIdx.x >> 6);
  int l = threadIdx.x & 63;
  int b = gw >> 10, a = gw & 1023;
  const float* qp = q + b * ND;
  const float* wp = Wd + (size_t)a * ND;
  float s = 0.0f;
  #pragma unroll
  for (int c = 0; c < 4; ++c){
    int off = c * 256 + l * 4;
    f32x4 q4 = *reinterpret_cast<const f32x4*>(qp + off);
    f32x4 w4 = *reinterpret_cast<const f32x4*>(wp + off);
    s += q4[0]*w4[0] + q4[1]*w4[1] + q4[2]*w4[2] + q4[3]*w4[3];
  }
  #pragma unroll
  for (int off = 1; off < 64; off <<= 1) s += __shfl_xor(s, off, 64);
  if (l == 0) V[gw] = s;
}

// ---- kernel 2: i8-pair grouped-product GEMM (R7 sync skeleton) -------------
// 256x128 tile, 8 waves (4M x 2N), per-wave 64x64. 16 K-groups of 64; per
// group: stage g+1 (6 gload_lds = 48 KB), read 16 frags, 48 MFMA i8 K=64
// (hh -> acc1; h*l + l*h -> acc2), one vmcnt(0)+barrier. U = sa*sb*(acc1 +
// acc2/256) in the epilogue.
__global__ __launch_bounds__(512, 2) void score_i8_kernel(
    const unsigned char* __restrict__ Kq_h,
    const unsigned char* __restrict__ Kq_l,
    const unsigned char* __restrict__ Wq_h,
    const unsigned char* __restrict__ Wq_l,
    const float* __restrict__ sA, const float* __restrict__ sB,
    const float* __restrict__ Vb, const float* __restrict__ vw,
    float* __restrict__ e_part)
{
  __shared__ __align__(16) unsigned char shb[98304];  // 2 bufs x 48 KB
  __shared__ float ebuf[2][256];
  __shared__ float sAl[256];
  __shared__ float sBl[128];

  const int t = threadIdx.x;
  const int w = t >> 6, l = t & 63;
  const int l15 = l & 15, lg = l >> 4;
  const int wr = w >> 1, wc = w & 1;

  // XCD-bijective swizzle: 8 N-chunks of one M-tile land on one XCD.
  const int orig = blockIdx.x;                 // 0..2047
  const int xcd = orig & 7;
  const int s0 = orig >> 3;
  const int nchunk = s0 & 7;
  const int mtile = ((s0 >> 3) << 3) | xcd;    // [0,256)
  const int row0 = mtile << 8;
  const int nb0 = nchunk << 7;
  const int bb = row0 >> 11;

  const unsigned char* Asrc_h = Kq_h + ((size_t)mtile << 18);
  const unsigned char* Asrc_l = Kq_l + ((size_t)mtile << 18);
  const size_t boff = ((size_t)(nchunk >> 1) << 18) + ((size_t)(nchunk & 1) << 13);
  const unsigned char* Bsrc_h = Wq_h + boff;
  const unsigned char* Bsrc_l = Wq_l + boff;

  // frag ds_read offsets (16 B each; +1024 per mf/nf step)
  const int swz0 = ((l15 & 1) << 2) | (lg ^ ((l15 >> 1) & 3));
  const int aoff0 = (wr << 12) + ((l15 >> 1) << 7) + (swz0 << 4);
  const int boff0 = (wc << 12) + ((l15 >> 1) << 7) + (swz0 << 4);
  const int stoff = t << 4;

  i32x4 acc1[4][4], acc2[4][4];
  #pragma unroll
  for (int mf = 0; mf < 4; ++mf)
    #pragma unroll
    for (int nf = 0; nf < 4; ++nf){ acc1[mf][nf] = (i32x4)0; acc2[mf][nf] = (i32x4)0; }

  auto stage = [&](int g, int bufW){
    const size_t gb = (size_t)g << 14;
    unsigned char* d = shb + bufW;
    gload_lds16(Asrc_h + gb + stoff,        d + stoff);
    gload_lds16(Asrc_h + gb + 8192 + stoff, d + 8192 + stoff);
    gload_lds16(Asrc_l + gb + stoff,        d + 16384 + stoff);
    gload_lds16(Asrc_l + gb + 8192 + stoff, d + 24576 + stoff);
    gload_lds16(Bsrc_h + gb + stoff,        d + 32768 + stoff);
    gload_lds16(Bsrc_l + gb + stoff,        d + 40960 + stoff);
  };

  // prologue: stage group 0 -> buf0; scales -> LDS; full drain+sync
  stage(0, 0);
  if (t < 256) sAl[t] = sA[row0 + t];
  if (t < 128) sBl[t] = sB[nb0 + t];
  __syncthreads();

  #pragma unroll 1
  for (int g = 0; g < 16; ++g){
    const int bufR = (g & 1) * 49152;
    const int bufW = 49152 - bufR;
    if (g < 15) stage(g + 1, bufW);

    const unsigned char* base = shb + bufR;
    i32x4 Ah[4], Al[4], Bh[4], Bl[4];
    #pragma unroll
    for (int mf = 0; mf < 4; ++mf){
      Ah[mf] = *reinterpret_cast<const i32x4*>(base + aoff0 + mf * 1024);
      Al[mf] = *reinterpret_cast<const i32x4*>(base + 16384 + aoff0 + mf * 1024);
    }
    #pragma unroll
    for (int nf = 0; nf < 4; ++nf){
      Bh[nf] = *reinterpret_cast<const i32x4*>(base + 32768 + boff0 + nf * 1024);
      Bl[nf] = *reinterpret_cast<const i32x4*>(base + 40960 + boff0 + nf * 1024);
    }
    __builtin_amdgcn_s_setprio(1);
    #pragma unroll
    for (int nf = 0; nf < 4; ++nf)
      #pragma unroll
      for (int mf = 0; mf < 4; ++mf)
        acc1[mf][nf] = __builtin_amdgcn_mfma_i32_16x16x64_i8(Ah[mf], Bh[nf], acc1[mf][nf], 0, 0, 0);
    #pragma unroll
    for (int nf = 0; nf < 4; ++nf)
      #pragma unroll
      for (int mf = 0; mf < 4; ++mf)
        acc2[mf][nf] = __builtin_amdgcn_mfma_i32_16x16x64_i8(Ah[mf], Bl[nf], acc2[mf][nf], 0, 0, 0);
    #pragma unroll
    for (int nf = 0; nf < 4; ++nf)
      #pragma unroll
      for (int mf = 0; mf < 4; ++mf)
        acc2[mf][nf] = __builtin_amdgcn_mfma_i32_16x16x64_i8(Al[mf], Bh[nf], acc2[mf][nf], 0, 0, 0);
    __builtin_amdgcn_s_setprio(0);

    VMCNT0();     // drain this wave's g+1 staging (issued at group top)
    BARRIER();    // cross-wave visibility before next group's reads
  }

  // epilogue: U = sa*sb*(acc1 + acc2/256); partial e over 128 N-cols
  float sav[16];
  #pragma unroll
  for (int mf = 0; mf < 4; ++mf)
    #pragma unroll
    for (int i = 0; i < 4; ++i)
      sav[(mf << 2) + i] = sAl[(wr << 6) + (mf << 4) + (lg << 2) + i];

  float er[16];
  #pragma unroll
  for (int j = 0; j < 16; ++j) er[j] = 0.0f;
  #pragma unroll
  for (int nf = 0; nf < 4; ++nf){
    const int nl = (wc << 6) + (nf << 4) + l15;
    const int n = nb0 + nl;
    const float sb = sBl[nl];
    const float Vl = Vb[bb * NA + n];
    const float vwl = vw[n];
    #pragma unroll
    for (int mf = 0; mf < 4; ++mf)
      #pragma unroll
      for (int i = 0; i < 4; ++i){
        float U = sav[(mf << 2) + i] * sb *
                  ((float)acc1[mf][nf][i] + (float)acc2[mf][nf][i] * 0.00390625f);
        er[(mf << 2) + i] += tanh_fast(U + Vl) * vwl;
      }
  }
  #pragma unroll
  for (int j = 0; j < 16; ++j){
    #pragma unroll
    for (int off = 1; off < 16; off <<= 1)
      er[j] += __shfl_xor(er[j], off, 64);
  }
  if (l15 == 0){
    #pragma unroll
    for (int mf = 0; mf < 4; ++mf)
      #pragma unroll
      for (int i = 0; i < 4; ++i)
        ebuf[wc][(wr << 6) + (mf << 4) + (lg << 2) + i] = er[(mf << 2) + i];
  }
  __syncthreads();
  if (t < 256)
    e_part[(size_t)nchunk * MROWS + row0 + t] = ebuf[0][t] + ebuf[1][t];
}

// ---- kernel 3: sum 8 partials + softmax over S ------------------------------
__global__ __launch_bounds__(256) void softmax_kernel(
    const float* __restrict__ e_part, float* __restrict__ a)
{
  __shared__ float red[4];
  const int b = blockIdx.x;
  const int t = threadIdx.x;
  const int l = t & 63, w = t >> 6;
  const float* ep = e_part + b * NS + t * 8;
  float v[8];
  #pragma unroll
  for (int j = 0; j < 8; ++j) v[j] = 0.0f;
  #pragma unroll
  for (int c = 0; c < 8; ++c){
    f32x4 x0 = *reinterpret_cast<const f32x4*>(ep + (size_t)c * MROWS);
    f32x4 x1 = *reinterpret_cast<const f32x4*>(ep + (size_t)c * MROWS + 4);
    #pragma unroll
    for (int j = 0; j < 4; ++j){ v[j] += x0[j]; v[4 + j] += x1[j]; }
  }

  float m = v[0];
  #pragma unroll
  for (int j = 1; j < 8; ++j) m = fmaxf(m, v[j]);
  #pragma unroll
  for (int off = 1; off < 64; off <<= 1) m = fmaxf(m, __shfl_xor(m, off, 64));
  if (l == 0) red[w] = m;
  __syncthreads();
  m = fmaxf(fmaxf(red[0], red[1]), fmaxf(red[2], red[3]));
  __syncthreads();

  float ex[8];
  float ssum = 0.0f;
  #pragma unroll
  for (int j = 0; j < 8; ++j){ ex[j] = __expf(v[j] - m); ssum += ex[j]; }
  #pragma unroll
  for (int off = 1; off < 64; off <<= 1) ssum += __shfl_xor(ssum, off, 64);
  if (l == 0) red[w] = ssum;
  __syncthreads();
  ssum = red[0] + red[1] + red[2] + red[3];
  float inv = 1.0f / ssum;

  float o[8];
  #pragma unroll
  for (int j = 0; j < 8; ++j) o[j] = ex[j] * inv;
  float* ap = a + b * NS + t * 8;
  *reinterpret_cast<f32x4*>(ap)     = *reinterpret_cast<f32x4*>(&o[0]);
  *reinterpret_cast<f32x4*>(ap + 4) = *reinterpret_cast<f32x4*>(&o[4]);
}

// ---- kernel 4a: partial context, dequant h+l from images -------------------
__global__ __launch_bounds__(256) void ctx_partial_i8_kernel(
    const float* __restrict__ a, const unsigned char* __restrict__ Kq_h,
    const unsigned char* __restrict__ Kq_l, const float* __restrict__ sA,
    float* __restrict__ part)
{
  const int bid = blockIdx.x;            // mtile 0..255 = b*8+sc
  const int t = threadIdx.x;             // covers e-cols [4t, 4t+4)
  const int g = t >> 4;
  const int kb = (t >> 2) & 3;
  const size_t ibase = ((size_t)bid << 18) + ((size_t)g << 14) + ((size_t)(t & 3) << 2);
  const float* ap = a + bid * 256;
  const float* sp = sA + bid * 256;
  f32x4 accv = (f32x4)0.0f;
  for (int si = 0; si < 256; ++si){
    const int rp = si >> 1, cc = si & 1;
    const size_t addr = ibase + ((size_t)rp << 7)
                      + ((size_t)(((cc << 2) | (kb ^ (rp & 3))) << 4));
    const int h32 = *reinterpret_cast<const int*>(Kq_h + addr);
    const int l32 = *reinterpret_cast<const int*>(Kq_l + addr);
    const float sa = sp[si];
    const float t1 = ap[si] * sa;
    const float t2 = t1 * 0.00390625f;
    #pragma unroll
    for (int j = 0; j < 4; ++j){
      int hj = (h32 << ((3 - j) * 8)) >> 24;
      int lj = (l32 << ((3 - j) * 8)) >> 24;
      accv[j] += t1 * (float)hj + t2 * (float)lj;
    }
  }
  *reinterpret_cast<f32x4*>(part + (size_t)bid * NE + t * 4) = accv;
}

// ---- kernel 4b: deterministic reduce of partials ----------------------------
__global__ __launch_bounds__(256) void ctx_reduce_kernel(
    const float* __restrict__ part, float* __restrict__ out)
{
  const int b = blockIdx.x;
  const int t = threadIdx.x;
  f32x4 s = (f32x4)0.0f;
  #pragma unroll
  for (int sc = 0; sc < 8; ++sc)
    s += *reinterpret_cast<const f32x4*>(part + (size_t)((b << 3) + sc) * NE + t * 4);
  *reinterpret_cast<f32x4*>(out + b * NE + t * 4) = s;
}

extern "C" void kernel_launch(void* const* d_in, const int* in_sizes, int n_in,
                              void* d_out, int out_size, void* d_ws, size_t ws_size,
                              hipStream_t stream)
{
  const float* keys = (const float*)d_in[0];
  const float* q    = (const float*)d_in[1];
  const float* We   = (const float*)d_in[2];
  const float* Wd   = (const float*)d_in[3];
  const float* vw   = (const float*)d_in[4];
  float* out = (float*)d_out;

  char* ws = (char*)d_ws;
  const size_t MB = 1024 * 1024;
  unsigned char* Wq_h = (unsigned char*)(ws);               // 1 MB
  unsigned char* Wq_l = (unsigned char*)(ws + 1 * MB);      // 1 MB
  float* sB     = (float*)(ws + 2 * MB);                    // 4 KB
  float* sA     = (float*)(ws + 2 * MB + 65536);            // 256 KB
  float* Vb     = (float*)(ws + 2 * MB + 393216);           // 128 KB
  float* e_part = (float*)(ws + 4 * MB);                    // 2 MB
  float* a      = (float*)(ws + 6 * MB);                    // 256 KB
  unsigned char* Kq_h = (unsigned char*)(ws + 8 * MB);      // 64 MB
  unsigned char* Kq_l = (unsigned char*)(ws + 72 * MB);     // 64 MB
  float* part   = e_part;  // aliased: e_part dead after softmax

  quant_kernel<<<256,   256, 0, stream>>>(We,   Wq_h, Wq_l, sB);
  quant_kernel<<<16384, 256, 0, stream>>>(keys, Kq_h, Kq_l, sA);
  v_kernel<<<(NB * NA) / 4, 256, 0, stream>>>(q, Wd, Vb);
  score_i8_kernel<<<2048, 512, 0, stream>>>(Kq_h, Kq_l, Wq_h, Wq_l,
                                            sA, sB, Vb, vw, e_part);
  softmax_kernel<<<NB, 256, 0, stream>>>(e_part, a);
  ctx_partial_i8_kernel<<<NB * 8, 256, 0, stream>>>(a, Kq_h, Kq_l, sA, part);
  ctx_reduce_kernel<<<NB, 256, 0, stream>>>(part, out);
}